// Round 15
// baseline (263.115 us; speedup 1.0000x reference)
//
#include <hip/hip_runtime.h>
#include <math.h>

#define NPTS    131072
#define PPB     32            // points per block (4 waves x 8 points)
#define THREADS 256
#define NBLK    (NPTS / PPB)  // 4096
#define HOFF    (7 * 16384)   // head-weight offset in wsW (bf16 elems)
#define HSZ     (32 * 128)    // head block: 32 rows (6 used), 128 k
#define ZOFF    (HOFF + HSZ)  // zero page: 256 u16 = 128 floats of 0.0f

typedef __attribute__((ext_vector_type(8)))  short short8;
typedef __attribute__((ext_vector_type(16))) float f32x16;

union b8cv { short8 v; unsigned u[4]; };

__device__ __forceinline__ unsigned short f2bf(float f) {
  unsigned u = __float_as_uint(f);
  unsigned r = (u + 0x7fffu + ((u >> 16) & 1u)) >> 16;
  return (unsigned short)r;
}
#if defined(__has_builtin)
#if __has_builtin(__builtin_amdgcn_cvt_pk_bf16_f32)
#define HAVE_PK_BF16 1
#endif
#endif
__device__ __forceinline__ unsigned pk2(float lo, float hi) {
#ifdef HAVE_PK_BF16
  auto v = __builtin_amdgcn_cvt_pk_bf16_f32(lo, hi);
  unsigned u; __builtin_memcpy(&u, &v, 4); return u;
#else
  return (unsigned)f2bf(lo) | ((unsigned)f2bf(hi) << 16);
#endif
}
__device__ __forceinline__ void gld16(const unsigned short* g, unsigned short* l) {
  __builtin_amdgcn_global_load_lds(
      (const __attribute__((address_space(1))) unsigned int*)(g),
      (__attribute__((address_space(3))) unsigned int*)(l), 16, 0, 0);
}
// broadcast the value-lane (lane & ~3) element of each 4-lane group: DPP quad_perm[0,0,0,0]
__device__ __forceinline__ float qbcast0(float v) {
  return __int_as_float(
      __builtin_amdgcn_mov_dpp(__float_as_int(v), 0x000, 0xf, 0xf, true));
}
__device__ __forceinline__ void cross3(const float a[3], const float b[3], float o[3]) {
  o[0] = a[1]*b[2] - a[2]*b[1];
  o[1] = a[2]*b[0] - a[0]*b[2];
  o[2] = a[0]*b[1] - a[1]*b[0];
}
__device__ __forceinline__ float dot3(const float a[3], const float b[3]) {
  return a[0]*b[0] + a[1]*b[1] + a[2]*b[2];
}

// ---- weights -> bf16 workspace: 7x[128c][128k] + heads 32x128 + zero page ----
__global__ void convert_weights(const float* __restrict__ W_in,
                                const float* __restrict__ Ws,
                                const float* __restrict__ Ww,
                                const float* __restrict__ Wv,
                                unsigned short* __restrict__ wsW) {
  int idx = blockIdx.x * 256 + threadIdx.x;
  if (idx >= ZOFF + 256) return;
  if (idx >= ZOFF) { wsW[idx] = 0; return; }   // zero page (bias for tangent lanes)
  float v;
  if (idx < HOFF) {
    int l = idx >> 14, r = idx & 16383, c = r >> 7, k = r & 127;
    if (l == 0) v = (k < 39) ? W_in[c * 39 + k] : 0.0f;
    else        v = Ws[(l - 1) * 16384 + c * 128 + k];
  } else {
    int r = idx - HOFF, o = r >> 7, k = r & 127;
    v = (o < 3) ? Ww[o * 128 + k] : (o < 6) ? Wv[(o - 3) * 128 + k] : 0.0f;
  }
  wsW[idx] = f2bf(v);
}

// DMA a 64-col half-layer (16 KB) into an LDS slot, XOR-chunk-swizzled:
// slot row R, chunk-pos chs holds global chunk chs^(R&15).
__device__ __forceinline__ void dma_half(const unsigned short* __restrict__ g,
                                         unsigned short* lds, int tid) {
  #pragma unroll
  for (int i = 0; i < 4; ++i) {
    int flat = i * 256 + tid;
    int R = flat >> 4, chs = flat & 15, ch = chs ^ (R & 15);
    gld16(g + R * 128 + ch * 8, lds + flat * 8);
  }
}

// One MLP layer (round-11 skeleton), half-slot pipelined, phase-split
// accumulators, typed short8 activation registers (direct MFMA operands).
// A = weights read at bit-2/3-swapped row sig => next-layer B-frag IS
// pregv[ks]. Phase 2 writes pregv[4..7] in place (old pregv fully read).
// Bias: uniform bg (real) + bgz (zero page); per-lane select done HERE so
// the pointer pair is dead after acc-init (no long-lived VGPRs).
// Activation via DPP quad-broadcast (3 VALU, 0 SALU per element).
template <int NKS, bool LEAKY, bool HASNEXT>
__device__ __forceinline__ void mlp_layer(short8 (&pregv)[8],
                                          unsigned short* s0, unsigned short* s1,
                                          const float* __restrict__ bg,
                                          const float* __restrict__ bgz,
                                          const unsigned short* __restrict__ Wthis,
                                          const unsigned short* __restrict__ Wnext,
                                          int sig, int h, int tid, int lane) {
  // stage this layer's upper half (cols 64-127) into s1; drained at mid-sync
  dma_half(Wthis + 64 * 128, s1, tid);

  const int sw15 = sig & 15;
  short8 tmp[4];                      // phase-1 results (units 0-63)

  // ---- phase 1: output units 0-63 (tiles mt=0,1) from s0 ----
  {
    f32x16 acc[2];
    {
      const float* bgl = ((lane & 3) == 0) ? bg : bgz;   // dies after this block
      #pragma unroll
      for (int mt = 0; mt < 2; ++mt)
        #pragma unroll
        for (int q = 0; q < 4; ++q) {
          float4 bb = *(const float4*)(bgl + 32*mt + 16*(q>>1) + 8*h + 4*(q&1));
          acc[mt][4*q+0] = bb.x;
          acc[mt][4*q+1] = bb.y;
          acc[mt][4*q+2] = bb.z;
          acc[mt][4*q+3] = bb.w;
        }
    }
    #pragma unroll
    for (int ks = 0; ks < NKS; ++ks) {
      #pragma unroll
      for (int m = 0; m < 2; ++m) {
        short8 af = *(const short8*)(s0 + (m*32+sig)*128 + (((2*ks+h)^sw15)<<3));
        acc[m] = __builtin_amdgcn_mfma_f32_32x32x16_bf16(af, pregv[ks], acc[m], 0, 0, 0);
      }
    }
    #pragma unroll
    for (int mt = 0; mt < 2; ++mt)
      #pragma unroll
      for (int qh = 0; qh < 2; ++qh) {
        b8cv cv;
        #pragma unroll
        for (int qs = 0; qs < 2; ++qs) {
          int q = 2*qh + qs;
          float pr[4];
          #pragma unroll
          for (int e2 = 0; e2 < 4; ++e2) {
            float post = acc[mt][4*q + e2];
            float vraw = qbcast0(post);
            pr[e2] = LEAKY ? (vraw > 0.0f ? post : post * 0.01f)
                           : (vraw > 0.0f ? post : 0.0f);
          }
          cv.u[2*qs]     = pk2(pr[0], pr[1]);
          cv.u[2*qs + 1] = pk2(pr[2], pr[3]);
        }
        tmp[2*mt + qh] = cv.v;
      }
  }

  __syncthreads();                       // s0 reads done; drains s1 DMA too
  if (HASNEXT) dma_half(Wnext, s0, tid); // next layer's cols 0-63

  // ---- phase 2: output units 64-127 (tiles mt=2,3) from s1 ----
  {
    f32x16 acc[2];
    {
      const float* bgl = ((lane & 3) == 0) ? bg : bgz;
      #pragma unroll
      for (int mt = 0; mt < 2; ++mt)
        #pragma unroll
        for (int q = 0; q < 4; ++q) {
          float4 bb = *(const float4*)(bgl + 32*(2+mt) + 16*(q>>1) + 8*h + 4*(q&1));
          acc[mt][4*q+0] = bb.x;
          acc[mt][4*q+1] = bb.y;
          acc[mt][4*q+2] = bb.z;
          acc[mt][4*q+3] = bb.w;
        }
    }
    #pragma unroll
    for (int ks = 0; ks < NKS; ++ks) {
      #pragma unroll
      for (int m = 0; m < 2; ++m) {
        short8 af = *(const short8*)(s1 + (m*32+sig)*128 + (((2*ks+h)^sw15)<<3));
        acc[m] = __builtin_amdgcn_mfma_f32_32x32x16_bf16(af, pregv[ks], acc[m], 0, 0, 0);
      }
    }
    // old pregv fully consumed -> write phase-2 results directly
    #pragma unroll
    for (int mt = 0; mt < 2; ++mt)
      #pragma unroll
      for (int qh = 0; qh < 2; ++qh) {
        b8cv cv;
        #pragma unroll
        for (int qs = 0; qs < 2; ++qs) {
          int q = 2*qh + qs;
          float pr[4];
          #pragma unroll
          for (int e2 = 0; e2 < 4; ++e2) {
            float post = acc[mt][4*q + e2];
            float vraw = qbcast0(post);
            pr[e2] = LEAKY ? (vraw > 0.0f ? post : post * 0.01f)
                           : (vraw > 0.0f ? post : 0.0f);
          }
          cv.u[2*qs]     = pk2(pr[0], pr[1]);
          cv.u[2*qs + 1] = pk2(pr[2], pr[3]);
        }
        pregv[4 + 2*mt + qh] = cv.v;
      }
  }

  #pragma unroll
  for (int i = 0; i < 4; ++i) pregv[i] = tmp[i];
  __syncthreads();                       // s1 reads done; drains s0 DMA
}

__global__ __launch_bounds__(THREADS, 4)
void nerfies_mfma(const float* __restrict__ x,
                  const float* __restrict__ b_in,
                  const float* __restrict__ bs,
                  const float* __restrict__ bw,
                  const float* __restrict__ bv,
                  const unsigned short* __restrict__ wsW,
                  const int* __restrict__ iterp,
                  float* __restrict__ out)
{
  __shared__ __align__(16) unsigned short sWl[2][64 * 128];  // 2x16 KB half-slots
  float* sH = (float*)sWl[1];                                // heads alias slot 1

  const int tid  = threadIdx.x;
  const int lane = tid & 63;
  const int wv   = tid >> 6;
  const int c32  = lane & 31;
  const int h    = lane >> 5;
  const int p0   = blockIdx.x * PPB;
  // sigma: swap bits 2<->3 (A-row permutation making next-layer B = identity)
  const int sig  = (c32 & 0x13) | ((c32 & 4) << 1) | ((c32 & 8) >> 1);
  const float* bgz = (const float*)(wsW + ZOFF);   // 128 floats of 0.0 (uniform)

  // prologue: stage layer-0 cols 0-63 into slot 0 (covered by posenc below)
  dma_half(wsW, sWl[0], tid);

  // this lane's act row: r = c32, point = wv*8 + (c32>>2), tangent d = c32&3
  const int d  = c32 & 3;
  const int gp = p0 + wv * 8 + (c32 >> 2);
  float X[3] = { x[gp * 3 + 0], x[gp * 3 + 1], x[gp * 3 + 2] };

  int iraw = iterp[0];
  float it = (iraw > 0 && iraw < 100000000) ? (float)iraw : ((const float*)iterp)[0];
  const float aM = 6.0f * it / 3000.0f;

  // ---- posenc into packed act regs (B-identity unit ordering) ----
  short8 pregv[8];
  #pragma unroll
  for (int j = 4; j < 8; ++j) pregv[j] = (short8)0;
  #pragma unroll
  for (int j = 0; j < 4; ++j) {
    b8cv cv;
    #pragma unroll
    for (int ii = 0; ii < 4; ++ii) {
      int i = 4*j + ii;
      int mt = i >> 3, rr = i & 7, q = rr >> 1, s = rr & 1;
      int u0 = 32*mt + 16*(q>>1) + 8*h + 4*(q&1) + 2*s;
      float vp[2];
      #pragma unroll
      for (int ci = 0; ci < 2; ++ci) {
        int c = u0 + ci;
        float val = 0.0f;
        if (c < 3) {
          val = (d == 0) ? X[c] : ((c == d - 1) ? 1.0f : 0.0f);
        } else if (c < 39) {
          int kk = c - 3;
          int a  = kk / 12;
          int rm = kk - a * 12;
          int t  = rm / 6;
          int jf = rm - t * 6;
          float e2 = exp2f((float)(jf - 3));
          float mj = e2 * 3.14f;
          float tt = fminf(fmaxf(aM - (float)jf, 0.0f), 1.0f);
          float wj = (1.0f - __builtin_amdgcn_cosf(tt * 0.49974652f)) * 0.5f;
          float rev = X[a] * (e2 * 0.49974652f);
          float fr  = rev - floorf(rev);
          float sv = __builtin_amdgcn_sinf(fr);
          float cvv = __builtin_amdgcn_cosf(fr);
          if (d == 0)          val = (t == 0 ? sv : cvv) * wj;
          else if (a == d - 1) val = (t == 0 ? cvv : -sv) * (mj * wj);
        }
        vp[ci] = val;
      }
      cv.u[ii] = pk2(vp[0], vp[1]);
    }
    pregv[j] = cv.v;
  }
  __syncthreads();   // slot0 (layer-0 lower half) landed

  // 7 fully-unrolled layer calls; bias pointers stay uniform (SGPR) here
  mlp_layer<3, true , true >(pregv, sWl[0], sWl[1], b_in,       bgz, wsW + 0*16384, wsW + 1*16384, sig, h, tid, lane);
  mlp_layer<8, false, true >(pregv, sWl[0], sWl[1], bs + 0*128, bgz, wsW + 1*16384, wsW + 2*16384, sig, h, tid, lane);
  mlp_layer<8, false, true >(pregv, sWl[0], sWl[1], bs + 1*128, bgz, wsW + 2*16384, wsW + 3*16384, sig, h, tid, lane);
  mlp_layer<8, false, true >(pregv, sWl[0], sWl[1], bs + 2*128, bgz, wsW + 3*16384, wsW + 4*16384, sig, h, tid, lane);
  mlp_layer<8, false, true >(pregv, sWl[0], sWl[1], bs + 3*128, bgz, wsW + 4*16384, wsW + 5*16384, sig, h, tid, lane);
  mlp_layer<8, false, true >(pregv, sWl[0], sWl[1], bs + 4*128, bgz, wsW + 5*16384, wsW + 6*16384, sig, h, tid, lane);
  mlp_layer<8, false, false>(pregv, sWl[0], sWl[1], bs + 5*128, bgz, wsW + 6*16384, wsW,           sig, h, tid, lane);

  // ---- heads: A = head weights (identity rows o) from L2, B = pregv ----
  {
    f32x16 hacc;
    #pragma unroll
    for (int e = 0; e < 16; ++e) hacc[e] = 0.0f;
    const unsigned short* hw = wsW + HOFF;
    #pragma unroll
    for (int ks = 0; ks < 8; ++ks) {
      short8 afrag = *(const short8*)(hw + c32 * 128 + ks * 16 + 8 * h);
      hacc = __builtin_amdgcn_mfma_f32_32x32x16_bf16(afrag, pregv[ks], hacc, 0, 0, 0);
    }
    int rg = wv * 32 + c32;
    if (h == 0) {   // regs 0..3 = outs o=0..3
      *(float4*)(sH + rg * 8) = make_float4(hacc[0], hacc[1], hacc[2], hacc[3]);
    } else {        // regs 0..1 = outs o=4,5
      *(float2*)(sH + rg * 8 + 4) = make_float2(hacc[0], hacc[1]);
    }
  }
  __syncthreads();

  // ---- SE(3) epilogue + forward-mode Jacobian: 8 points per wave ----
  if (lane < 8) {
    const int p  = wv * 8 + lane;
    const int gpp = p0 + p;
    float XX[3] = { x[gpp*3+0], x[gpp*3+1], x[gpp*3+2] };
    float w[3], v[3], dw[3][3], dv[3][3];
    const int rb = p * 4;
    #pragma unroll
    for (int i = 0; i < 3; ++i) {
      w[i] = sH[rb * 8 + i]     + bw[i];
      v[i] = sH[rb * 8 + 3 + i] + bv[i];
      #pragma unroll
      for (int dd = 0; dd < 3; ++dd) {
        dw[dd][i] = sH[(rb + 1 + dd) * 8 + i];
        dv[dd][i] = sH[(rb + 1 + dd) * 8 + 3 + i];
      }
    }
    float th  = sqrtf(w[0]*w[0] + w[1]*w[1] + w[2]*w[2]);
    float ith = 1.0f / th;
    float u[3]  = { w[0]*ith, w[1]*ith, w[2]*ith };
    float vh[3] = { v[0]*ith, v[1]*ith, v[2]*ith };
    float s = sinf(th), c = cosf(th);
    float C2 = 1.0f - c;
    float ths = th - s;
    float uxx[3]; cross3(u, XX, uxx);
    float udx = dot3(u, XX);
    float uxv[3]; cross3(u, vh, uxv);
    float udv = dot3(u, vh);
    #pragma unroll
    for (int i = 0; i < 3; ++i) {
      float Rx = XX[i] + s * uxx[i] + C2 * (u[i] * udx - XX[i]);
      float tt = th * vh[i] + C2 * uxv[i] + ths * (u[i] * udv - vh[i]);
      out[gpp*3 + i] = Rx + tt;
    }
    float* Jout = out + (size_t)NPTS * 3 + (size_t)gpp * 9;
    #pragma unroll
    for (int dd = 0; dd < 3; ++dd) {
      float dwv[3] = { dw[dd][0], dw[dd][1], dw[dd][2] };
      float dvv[3] = { dv[dd][0], dv[dd][1], dv[dd][2] };
      float dth = dot3(w, dwv) * ith;
      float du[3], dvhv[3];
      #pragma unroll
      for (int i = 0; i < 3; ++i) {
        du[i]   = (dwv[i] - u[i]  * dth) * ith;
        dvhv[i] = (dvv[i] - vh[i] * dth) * ith;
      }
      float ex[3] = { dd == 0 ? 1.0f : 0.0f, dd == 1 ? 1.0f : 0.0f, dd == 2 ? 1.0f : 0.0f };
      float dsv  = c  * dth;
      float dC2  = s  * dth;
      float dths = C2 * dth;
      float duxx[3]; cross3(du, XX, duxx);
      float uxe[3];  cross3(u, ex, uxe);
      float dudx = dot3(du, XX) + u[dd];
      float duxv[3]; cross3(du, vh, duxv);
      float uxdv[3]; cross3(u, dvhv, uxdv);
      float dudv = dot3(du, vh) + dot3(u, dvhv);
      #pragma unroll
      for (int i = 0; i < 3; ++i) {
        float dRx = ex[i] + dsv * uxx[i] + s * (duxx[i] + uxe[i])
                  + dC2 * (u[i] * udx - XX[i])
                  + C2 * (du[i] * udx + u[i] * dudx - ex[i]);
        float dt  = dth * vh[i] + th * dvhv[i] + dC2 * uxv[i]
                  + C2 * (duxv[i] + uxdv[i])
                  + dths * (u[i] * udv - vh[i])
                  + ths * (du[i] * udv + u[i] * dudv - dvhv[i]);
        Jout[i * 3 + dd] = dRx + dt;
      }
    }
  }
}

extern "C" void kernel_launch(void* const* d_in, const int* in_sizes, int n_in,
                              void* d_out, int out_size, void* d_ws, size_t ws_size,
                              hipStream_t stream) {
  const float* x    = (const float*)d_in[0];
  const float* W_in = (const float*)d_in[1];
  const float* b_in = (const float*)d_in[2];
  const float* Ws   = (const float*)d_in[3];
  const float* bs   = (const float*)d_in[4];
  const float* Ww   = (const float*)d_in[5];
  const float* bw   = (const float*)d_in[6];
  const float* Wv   = (const float*)d_in[7];
  const float* bv   = (const float*)d_in[8];
  const int*   itp  = (const int*)d_in[9];
  unsigned short* wsW = (unsigned short*)d_ws;   // (7*16384 + 4096 + 256) bf16

  convert_weights<<<dim3((ZOFF + 256 + 255) / 256), dim3(256), 0, stream>>>(
      W_in, Ws, Ww, Wv, wsW);
  nerfies_mfma<<<dim3(NBLK), dim3(THREADS), 0, stream>>>(
      x, b_in, bs, bw, bv, wsW, itp, (float*)d_out);
}

// Round 16
// 238.289 us; speedup vs baseline: 1.1042x; 1.1042x over previous
//
#include <hip/hip_runtime.h>
#include <math.h>

#define NPTS    131072
#define PPB     32            // points per block (4 waves x 8 points)
#define THREADS 256
#define NBLK    (NPTS / PPB)  // 4096
#define HOFF    (7 * 16384)   // head-weight offset in wsW (bf16 elems)
#define HSZ     (32 * 128)    // head block: 32 rows (6 used), 128 k

typedef __attribute__((ext_vector_type(8)))  short short8;
typedef __attribute__((ext_vector_type(16))) float f32x16;

union b8cv { short8 v; unsigned u[4]; };

__device__ __forceinline__ unsigned short f2bf(float f) {
  unsigned u = __float_as_uint(f);
  unsigned r = (u + 0x7fffu + ((u >> 16) & 1u)) >> 16;
  return (unsigned short)r;
}
#if defined(__has_builtin)
#if __has_builtin(__builtin_amdgcn_cvt_pk_bf16_f32)
#define HAVE_PK_BF16 1
#endif
#endif
__device__ __forceinline__ unsigned pk2(float lo, float hi) {
#ifdef HAVE_PK_BF16
  auto v = __builtin_amdgcn_cvt_pk_bf16_f32(lo, hi);
  unsigned u; __builtin_memcpy(&u, &v, 4); return u;
#else
  return (unsigned)f2bf(lo) | ((unsigned)f2bf(hi) << 16);
#endif
}
__device__ __forceinline__ void gld16(const unsigned short* g, unsigned short* l) {
  __builtin_amdgcn_global_load_lds(
      (const __attribute__((address_space(1))) unsigned int*)(g),
      (__attribute__((address_space(3))) unsigned int*)(l), 16, 0, 0);
}
// broadcast the value-lane (lane & ~3) element of each 4-lane group: DPP quad_perm[0,0,0,0]
__device__ __forceinline__ float qbcast0(float v) {
  return __int_as_float(
      __builtin_amdgcn_mov_dpp(__float_as_int(v), 0x000, 0xf, 0xf, true));
}
__device__ __forceinline__ void cross3(const float a[3], const float b[3], float o[3]) {
  o[0] = a[1]*b[2] - a[2]*b[1];
  o[1] = a[2]*b[0] - a[0]*b[2];
  o[2] = a[0]*b[1] - a[1]*b[0];
}
__device__ __forceinline__ float dot3(const float a[3], const float b[3]) {
  return a[0]*b[0] + a[1]*b[1] + a[2]*b[2];
}

// ---- weights -> bf16 workspace: 7x[128c][128k] identity + heads 32x128 ----
__global__ void convert_weights(const float* __restrict__ W_in,
                                const float* __restrict__ Ws,
                                const float* __restrict__ Ww,
                                const float* __restrict__ Wv,
                                unsigned short* __restrict__ wsW) {
  int idx = blockIdx.x * 256 + threadIdx.x;
  if (idx >= HOFF + HSZ) return;
  float v;
  if (idx < HOFF) {
    int l = idx >> 14, r = idx & 16383, c = r >> 7, k = r & 127;
    if (l == 0) v = (k < 39) ? W_in[c * 39 + k] : 0.0f;
    else        v = Ws[(l - 1) * 16384 + c * 128 + k];
  } else {
    int r = idx - HOFF, o = r >> 7, k = r & 127;
    v = (o < 3) ? Ww[o * 128 + k] : (o < 6) ? Wv[(o - 3) * 128 + k] : 0.0f;
  }
  wsW[idx] = f2bf(v);
}

// DMA a 64-col half-layer (16 KB) into an LDS slot, XOR-chunk-swizzled:
// slot row R, chunk-pos chs holds global chunk chs^(R&15).
__device__ __forceinline__ void dma_half(const unsigned short* __restrict__ g,
                                         unsigned short* lds, int tid) {
  #pragma unroll
  for (int i = 0; i < 4; ++i) {
    int flat = i * 256 + tid;
    int R = flat >> 4, chs = flat & 15, ch = chs ^ (R & 15);
    gld16(g + R * 128 + ch * 8, lds + flat * 8);
  }
}

// One MLP layer (round-11 skeleton, verbatim except activation), half-slot
// pipelined, phase-split accumulators, typed short8 activation registers
// (direct MFMA operands). A = weights read at bit-2/3-swapped row sig =>
// next-layer B-frag IS pregv[ks]. Phase 2 writes pregv[4..7] in place.
// Activation via DPP quad-broadcast (3 VALU, 0 SALU per element) -- the
// ONLY change vs the 198us round-11 kernel.
template <int NKS, bool LEAKY, bool HASNEXT>
__device__ __forceinline__ void mlp_layer(short8 (&pregv)[8],
                                          unsigned short* s0, unsigned short* s1,
                                          const float* __restrict__ bg,
                                          const unsigned short* __restrict__ Wthis,
                                          const unsigned short* __restrict__ Wnext,
                                          int sig, int h, int tid, int lane) {
  // stage this layer's upper half (cols 64-127) into s1; drained at mid-sync
  dma_half(Wthis + 64 * 128, s1, tid);

  const bool isv = (lane & 3) == 0;   // this lane's act row is a value row
  const int sw15 = sig & 15;
  short8 tmp[4];                      // phase-1 results (units 0-63)

  // ---- phase 1: output units 0-63 (tiles mt=0,1) from s0 ----
  {
    f32x16 acc[2];
    #pragma unroll
    for (int mt = 0; mt < 2; ++mt)
      #pragma unroll
      for (int q = 0; q < 4; ++q) {
        float4 bb = *(const float4*)(bg + 32*mt + 16*(q>>1) + 8*h + 4*(q&1));
        acc[mt][4*q+0] = isv ? bb.x : 0.0f;
        acc[mt][4*q+1] = isv ? bb.y : 0.0f;
        acc[mt][4*q+2] = isv ? bb.z : 0.0f;
        acc[mt][4*q+3] = isv ? bb.w : 0.0f;
      }
    #pragma unroll
    for (int ks = 0; ks < NKS; ++ks) {
      #pragma unroll
      for (int m = 0; m < 2; ++m) {
        short8 af = *(const short8*)(s0 + (m*32+sig)*128 + (((2*ks+h)^sw15)<<3));
        acc[m] = __builtin_amdgcn_mfma_f32_32x32x16_bf16(af, pregv[ks], acc[m], 0, 0, 0);
      }
    }
    #pragma unroll
    for (int mt = 0; mt < 2; ++mt)
      #pragma unroll
      for (int qh = 0; qh < 2; ++qh) {
        b8cv cv;
        #pragma unroll
        for (int qs = 0; qs < 2; ++qs) {
          int q = 2*qh + qs;
          float pr[4];
          #pragma unroll
          for (int e2 = 0; e2 < 4; ++e2) {
            float post = acc[mt][4*q + e2];
            float vraw = qbcast0(post);
            pr[e2] = LEAKY ? (vraw > 0.0f ? post : post * 0.01f)
                           : (vraw > 0.0f ? post : 0.0f);
          }
          cv.u[2*qs]     = pk2(pr[0], pr[1]);
          cv.u[2*qs + 1] = pk2(pr[2], pr[3]);
        }
        tmp[2*mt + qh] = cv.v;
      }
  }

  __syncthreads();                       // s0 reads done; drains s1 DMA too
  if (HASNEXT) dma_half(Wnext, s0, tid); // next layer's cols 0-63

  // ---- phase 2: output units 64-127 (tiles mt=2,3) from s1 ----
  {
    f32x16 acc[2];
    #pragma unroll
    for (int mt = 0; mt < 2; ++mt)
      #pragma unroll
      for (int q = 0; q < 4; ++q) {
        float4 bb = *(const float4*)(bg + 32*(2+mt) + 16*(q>>1) + 8*h + 4*(q&1));
        acc[mt][4*q+0] = isv ? bb.x : 0.0f;
        acc[mt][4*q+1] = isv ? bb.y : 0.0f;
        acc[mt][4*q+2] = isv ? bb.z : 0.0f;
        acc[mt][4*q+3] = isv ? bb.w : 0.0f;
      }
    #pragma unroll
    for (int ks = 0; ks < NKS; ++ks) {
      #pragma unroll
      for (int m = 0; m < 2; ++m) {
        short8 af = *(const short8*)(s1 + (m*32+sig)*128 + (((2*ks+h)^sw15)<<3));
        acc[m] = __builtin_amdgcn_mfma_f32_32x32x16_bf16(af, pregv[ks], acc[m], 0, 0, 0);
      }
    }
    // old pregv fully consumed -> write phase-2 results directly
    #pragma unroll
    for (int mt = 0; mt < 2; ++mt)
      #pragma unroll
      for (int qh = 0; qh < 2; ++qh) {
        b8cv cv;
        #pragma unroll
        for (int qs = 0; qs < 2; ++qs) {
          int q = 2*qh + qs;
          float pr[4];
          #pragma unroll
          for (int e2 = 0; e2 < 4; ++e2) {
            float post = acc[mt][4*q + e2];
            float vraw = qbcast0(post);
            pr[e2] = LEAKY ? (vraw > 0.0f ? post : post * 0.01f)
                           : (vraw > 0.0f ? post : 0.0f);
          }
          cv.u[2*qs]     = pk2(pr[0], pr[1]);
          cv.u[2*qs + 1] = pk2(pr[2], pr[3]);
        }
        pregv[4 + 2*mt + qh] = cv.v;
      }
  }

  #pragma unroll
  for (int i = 0; i < 4; ++i) pregv[i] = tmp[i];
  __syncthreads();                       // s1 reads done; drains s0 DMA
}

__global__ __launch_bounds__(THREADS, 4)
void nerfies_mfma(const float* __restrict__ x,
                  const float* __restrict__ b_in,
                  const float* __restrict__ bs,
                  const float* __restrict__ bw,
                  const float* __restrict__ bv,
                  const unsigned short* __restrict__ wsW,
                  const int* __restrict__ iterp,
                  float* __restrict__ out)
{
  __shared__ __align__(16) unsigned short sWl[2][64 * 128];  // 2x16 KB half-slots
  float* sH = (float*)sWl[1];                                // heads alias slot 1

  const int tid  = threadIdx.x;
  const int lane = tid & 63;
  const int wv   = tid >> 6;
  const int c32  = lane & 31;
  const int h    = lane >> 5;
  const int p0   = blockIdx.x * PPB;
  // sigma: swap bits 2<->3 (A-row permutation making next-layer B = identity)
  const int sig  = (c32 & 0x13) | ((c32 & 4) << 1) | ((c32 & 8) >> 1);

  // prologue: stage layer-0 cols 0-63 into slot 0 (covered by posenc below)
  dma_half(wsW, sWl[0], tid);

  // this lane's act row: r = c32, point = wv*8 + (c32>>2), tangent d = c32&3
  const int d  = c32 & 3;
  const int gp = p0 + wv * 8 + (c32 >> 2);
  float X[3] = { x[gp * 3 + 0], x[gp * 3 + 1], x[gp * 3 + 2] };

  int iraw = iterp[0];
  float it = (iraw > 0 && iraw < 100000000) ? (float)iraw : ((const float*)iterp)[0];
  const float aM = 6.0f * it / 3000.0f;

  // ---- posenc into packed act regs (B-identity unit ordering) ----
  short8 pregv[8];
  #pragma unroll
  for (int j = 4; j < 8; ++j) pregv[j] = (short8)0;
  #pragma unroll
  for (int j = 0; j < 4; ++j) {
    b8cv cv;
    #pragma unroll
    for (int ii = 0; ii < 4; ++ii) {
      int i = 4*j + ii;
      int mt = i >> 3, rr = i & 7, q = rr >> 1, s = rr & 1;
      int u0 = 32*mt + 16*(q>>1) + 8*h + 4*(q&1) + 2*s;
      float vp[2];
      #pragma unroll
      for (int ci = 0; ci < 2; ++ci) {
        int c = u0 + ci;
        float val = 0.0f;
        if (c < 3) {
          val = (d == 0) ? X[c] : ((c == d - 1) ? 1.0f : 0.0f);
        } else if (c < 39) {
          int kk = c - 3;
          int a  = kk / 12;
          int rm = kk - a * 12;
          int t  = rm / 6;
          int jf = rm - t * 6;
          float e2 = exp2f((float)(jf - 3));
          float mj = e2 * 3.14f;
          float tt = fminf(fmaxf(aM - (float)jf, 0.0f), 1.0f);
          float wj = (1.0f - __builtin_amdgcn_cosf(tt * 0.49974652f)) * 0.5f;
          float rev = X[a] * (e2 * 0.49974652f);
          float fr  = rev - floorf(rev);
          float sv = __builtin_amdgcn_sinf(fr);
          float cvv = __builtin_amdgcn_cosf(fr);
          if (d == 0)          val = (t == 0 ? sv : cvv) * wj;
          else if (a == d - 1) val = (t == 0 ? cvv : -sv) * (mj * wj);
        }
        vp[ci] = val;
      }
      cv.u[ii] = pk2(vp[0], vp[1]);
    }
    pregv[j] = cv.v;
  }
  __syncthreads();   // slot0 (layer-0 lower half) landed

  mlp_layer<3, true , true >(pregv, sWl[0], sWl[1], b_in,       wsW + 0*16384, wsW + 1*16384, sig, h, tid, lane);
  mlp_layer<8, false, true >(pregv, sWl[0], sWl[1], bs + 0*128, wsW + 1*16384, wsW + 2*16384, sig, h, tid, lane);
  mlp_layer<8, false, true >(pregv, sWl[0], sWl[1], bs + 1*128, wsW + 2*16384, wsW + 3*16384, sig, h, tid, lane);
  mlp_layer<8, false, true >(pregv, sWl[0], sWl[1], bs + 2*128, wsW + 3*16384, wsW + 4*16384, sig, h, tid, lane);
  mlp_layer<8, false, true >(pregv, sWl[0], sWl[1], bs + 3*128, wsW + 4*16384, wsW + 5*16384, sig, h, tid, lane);
  mlp_layer<8, false, true >(pregv, sWl[0], sWl[1], bs + 4*128, wsW + 5*16384, wsW + 6*16384, sig, h, tid, lane);
  mlp_layer<8, false, false>(pregv, sWl[0], sWl[1], bs + 5*128, wsW + 6*16384, wsW,           sig, h, tid, lane);

  // ---- heads: A = head weights (identity rows o) from L2, B = pregv ----
  {
    f32x16 hacc;
    #pragma unroll
    for (int e = 0; e < 16; ++e) hacc[e] = 0.0f;
    const unsigned short* hw = wsW + HOFF;
    #pragma unroll
    for (int ks = 0; ks < 8; ++ks) {
      short8 afrag = *(const short8*)(hw + c32 * 128 + ks * 16 + 8 * h);
      hacc = __builtin_amdgcn_mfma_f32_32x32x16_bf16(afrag, pregv[ks], hacc, 0, 0, 0);
    }
    int rg = wv * 32 + c32;
    if (h == 0) {   // regs 0..3 = outs o=0..3
      *(float4*)(sH + rg * 8) = make_float4(hacc[0], hacc[1], hacc[2], hacc[3]);
    } else {        // regs 0..1 = outs o=4,5
      *(float2*)(sH + rg * 8 + 4) = make_float2(hacc[0], hacc[1]);
    }
  }
  __syncthreads();

  // ---- SE(3) epilogue + forward-mode Jacobian: 8 points per wave ----
  if (lane < 8) {
    const int p  = wv * 8 + lane;
    const int gpp = p0 + p;
    float XX[3] = { x[gpp*3+0], x[gpp*3+1], x[gpp*3+2] };
    float w[3], v[3], dw[3][3], dv[3][3];
    const int rb = p * 4;
    #pragma unroll
    for (int i = 0; i < 3; ++i) {
      w[i] = sH[rb * 8 + i]     + bw[i];
      v[i] = sH[rb * 8 + 3 + i] + bv[i];
      #pragma unroll
      for (int dd = 0; dd < 3; ++dd) {
        dw[dd][i] = sH[(rb + 1 + dd) * 8 + i];
        dv[dd][i] = sH[(rb + 1 + dd) * 8 + 3 + i];
      }
    }
    float th  = sqrtf(w[0]*w[0] + w[1]*w[1] + w[2]*w[2]);
    float ith = 1.0f / th;
    float u[3]  = { w[0]*ith, w[1]*ith, w[2]*ith };
    float vh[3] = { v[0]*ith, v[1]*ith, v[2]*ith };
    float s = sinf(th), c = cosf(th);
    float C2 = 1.0f - c;
    float ths = th - s;
    float uxx[3]; cross3(u, XX, uxx);
    float udx = dot3(u, XX);
    float uxv[3]; cross3(u, vh, uxv);
    float udv = dot3(u, vh);
    #pragma unroll
    for (int i = 0; i < 3; ++i) {
      float Rx = XX[i] + s * uxx[i] + C2 * (u[i] * udx - XX[i]);
      float tt = th * vh[i] + C2 * uxv[i] + ths * (u[i] * udv - vh[i]);
      out[gpp*3 + i] = Rx + tt;
    }
    float* Jout = out + (size_t)NPTS * 3 + (size_t)gpp * 9;
    #pragma unroll
    for (int dd = 0; dd < 3; ++dd) {
      float dwv[3] = { dw[dd][0], dw[dd][1], dw[dd][2] };
      float dvv[3] = { dv[dd][0], dv[dd][1], dv[dd][2] };
      float dth = dot3(w, dwv) * ith;
      float du[3], dvhv[3];
      #pragma unroll
      for (int i = 0; i < 3; ++i) {
        du[i]   = (dwv[i] - u[i]  * dth) * ith;
        dvhv[i] = (dvv[i] - vh[i] * dth) * ith;
      }
      float ex[3] = { dd == 0 ? 1.0f : 0.0f, dd == 1 ? 1.0f : 0.0f, dd == 2 ? 1.0f : 0.0f };
      float dsv  = c  * dth;
      float dC2  = s  * dth;
      float dths = C2 * dth;
      float duxx[3]; cross3(du, XX, duxx);
      float uxe[3];  cross3(u, ex, uxe);
      float dudx = dot3(du, XX) + u[dd];
      float duxv[3]; cross3(du, vh, duxv);
      float uxdv[3]; cross3(u, dvhv, uxdv);
      float dudv = dot3(du, vh) + dot3(u, dvhv);
      #pragma unroll
      for (int i = 0; i < 3; ++i) {
        float dRx = ex[i] + dsv * uxx[i] + s * (duxx[i] + uxe[i])
                  + dC2 * (u[i] * udx - XX[i])
                  + C2 * (du[i] * udx + u[i] * dudx - ex[i]);
        float dt  = dth * vh[i] + th * dvhv[i] + dC2 * uxv[i]
                  + C2 * (duxv[i] + uxdv[i])
                  + dths * (u[i] * udv - vh[i])
                  + ths * (du[i] * udv + u[i] * dudv - dvhv[i]);
        Jout[i * 3 + dd] = dRx + dt;
      }
    }
  }
}

extern "C" void kernel_launch(void* const* d_in, const int* in_sizes, int n_in,
                              void* d_out, int out_size, void* d_ws, size_t ws_size,
                              hipStream_t stream) {
  const float* x    = (const float*)d_in[0];
  const float* W_in = (const float*)d_in[1];
  const float* b_in = (const float*)d_in[2];
  const float* Ws   = (const float*)d_in[3];
  const float* bs   = (const float*)d_in[4];
  const float* Ww   = (const float*)d_in[5];
  const float* bw   = (const float*)d_in[6];
  const float* Wv   = (const float*)d_in[7];
  const float* bv   = (const float*)d_in[8];
  const int*   itp  = (const int*)d_in[9];
  unsigned short* wsW = (unsigned short*)d_ws;   // (7*16384 + 4096) bf16

  convert_weights<<<dim3((HOFF + HSZ + 255) / 256), dim3(256), 0, stream>>>(
      W_in, Ws, Ww, Wv, wsW);
  nerfies_mfma<<<dim3(NBLK), dim3(THREADS), 0, stream>>>(
      x, b_in, bs, bw, bv, wsW, itp, (float*)d_out);
}